// Round 13
// baseline (3838.034 us; speedup 1.0000x reference)
//
#include <hip/hip_runtime.h>

// GIN forward. lin0 -> 3x [GINConv(sum-agg) -> Lin->BN->ReLU->Lin->BN->ReLU] -> mean-pool
// N=100000, E=1.6M, D=49 (pad LD=64), NG=512.
//
// Round-8..13: GEMM re-tiled (unbenched due to repeated GPU acquisition timeouts;
// resubmitting unchanged). Round-7's one-row-per-thread k_gemm was structurally
// starved: 1564 waves total (11% occupancy), 104 VGPR (row[52]+acc[52] never fit),
// 637 broadcast ds_read_b128 serially issued per wave. New mapping:
//   lane = output column, wave = 8 rows, block = 32 rows (grid 3125, 12500 waves).
//   A tile [32][64] + W [52][64] (zero-padded) in LDS; inner loop per k-quad =
//   4 conflict-free b32 W reads + 8 broadcast b128 A reads + 32 FMAs; acc[8].
//   BN+ReLU of the previous linear folds into A staging; BN stats reduced in LDS
//   per block, then one atomic pass (3125 blocks vs 12500 wave-atomics).
// k_lin0 same structure (DIN=56 -> 14 k-quads). k_agg/preproc/pool unchanged.

#define DV 49
#define LD 64
#define DIN 56
#define NGR 512
#define NLAY 3
#define BSH 7
#define BSZ 128
#define MAXNB 1024  // supports N <= 131072

__global__ void k_zero(int* __restrict__ ghist, int NB, float* __restrict__ stats) {
    int i = blockIdx.x * blockDim.x + threadIdx.x;
    int stride = gridDim.x * blockDim.x;
    for (int j = i; j < NB; j += stride) ghist[j] = 0;
    for (int j = i; j < NLAY * 2 * 128; j += stride) stats[j] = 0.f;
}

__global__ void k_hist_b(const int* __restrict__ dst, int E, int* __restrict__ ghist, int NB) {
    __shared__ int lh[MAXNB];
    int t = threadIdx.x;
    for (int i = t; i < NB; i += 256) lh[i] = 0;
    __syncthreads();
    int chunk = (E + gridDim.x - 1) / gridDim.x;
    int s = blockIdx.x * chunk, e = min(E, s + chunk);
    for (int i = s + t; i < e; i += 256) atomicAdd(&lh[dst[i] >> BSH], 1);
    __syncthreads();
    for (int i = t; i < NB; i += 256)
        if (lh[i]) atomicAdd(&ghist[i], lh[i]);
}

__global__ void k_scanb(const int* __restrict__ g, int NB, int* __restrict__ bstart,
                        int* __restrict__ cursor) {
    __shared__ int sm[256];
    __shared__ int carry;
    int t = threadIdx.x;
    if (t == 0) carry = 0;
    __syncthreads();
    for (int base = 0; base < NB; base += 256) {
        int v = (base + t < NB) ? g[base + t] : 0;
        sm[t] = v;
        __syncthreads();
        for (int off = 1; off < 256; off <<= 1) {
            int x = (t >= off) ? sm[t - off] : 0;
            __syncthreads();
            sm[t] += x;
            __syncthreads();
        }
        int excl = sm[t] - v + carry;
        if (base + t < NB) { bstart[base + t] = excl; cursor[base + t] = excl; }
        int tot = sm[255];
        __syncthreads();
        if (t == 0) carry += tot;
        __syncthreads();
    }
    if (t == 0) bstart[NB] = carry;
}

__global__ void k_scatter_b(const int* __restrict__ src, const int* __restrict__ dst, int E,
                            int* __restrict__ cursor, unsigned int* __restrict__ ep, int NB) {
    __shared__ int lcount[MAXNB];
    __shared__ int lbase[MAXNB];
    __shared__ int lofs[MAXNB];
    int t = threadIdx.x;
    for (int i = t; i < NB; i += 256) { lcount[i] = 0; lofs[i] = 0; }
    __syncthreads();
    int chunk = (E + gridDim.x - 1) / gridDim.x;
    int s = blockIdx.x * chunk, e = min(E, s + chunk);
    for (int i = s + t; i < e; i += 256) atomicAdd(&lcount[dst[i] >> BSH], 1);
    __syncthreads();
    for (int i = t; i < NB; i += 256)
        if (lcount[i]) lbase[i] = atomicAdd(&cursor[i], lcount[i]);
    __syncthreads();
    for (int i = s + t; i < e; i += 256) {
        int d = dst[i];
        int b = d >> BSH;
        int pos = lbase[b] + atomicAdd(&lofs[b], 1);
        ep[pos] = (unsigned)src[i] | ((unsigned)(d & (BSZ - 1)) << 20);
    }
}

// One block per bucket: counting-sort packed records by dstLocal -> per-node CSR + rowptr.
__global__ void k_sortb(const unsigned int* __restrict__ ep, const int* __restrict__ bstart,
                        int* __restrict__ csr, int* __restrict__ rowptr, int N, int NB) {
    __shared__ int cnt[BSZ];
    __shared__ int pref[BSZ];
    int t = threadIdx.x;
    int b = blockIdx.x;
    int es = bstart[b], ee = bstart[b + 1];
    if (t < BSZ) cnt[t] = 0;
    __syncthreads();
    for (int i = es + t; i < ee; i += 256) atomicAdd(&cnt[(ep[i] >> 20) & 127], 1);
    __syncthreads();
    if (t < BSZ) pref[t] = cnt[t];
    __syncthreads();
    for (int off = 1; off < BSZ; off <<= 1) {
        int x = 0;
        if (t < BSZ && t >= off) x = pref[t - off];
        __syncthreads();
        if (t < BSZ && t >= off) pref[t] += x;
        __syncthreads();
    }
    // exclusive prefix
    if (t < BSZ) pref[t] -= cnt[t];
    __syncthreads();
    if (t < BSZ) {
        int n = (b << BSH) + t;
        if (n < N) rowptr[n] = es + pref[t];
    }
    if (b == NB - 1 && t == 0) rowptr[N] = ee;
    __syncthreads();
    for (int i = es + t; i < ee; i += 256) {
        unsigned p = ep[i];
        int pos = es + atomicAdd(&pref[(p >> 20) & 127], 1);
        csr[pos] = (int)(p & 0xFFFFFu);
    }
}

// Tiled lin0: block = 32 rows, wave = 8 rows, lane = output col. x:[N][56] @ W0:[56][49].
__global__ __launch_bounds__(256, 4)
void k_lin0(const float* __restrict__ x, const float* __restrict__ W0,
            const float* __restrict__ b0, float* __restrict__ h, int N) {
    __shared__ __align__(16) float Asm[32 * DIN];
    __shared__ __align__(16) float Wsm[DIN * 64];
    __shared__ float pb[64];
    int t = threadIdx.x;
    int w = t >> 6, l = t & 63;
    int n0 = blockIdx.x << 5;
    if (t < 64) pb[t] = (t < DV) ? b0[t] : 0.f;
    for (int idx = t; idx < DIN * 64; idx += 256) {
        int k = idx >> 6, c = idx & 63;
        Wsm[idx] = (c < DV) ? W0[k * DV + c] : 0.f;
    }
    for (int idx = t; idx < 32 * (DIN / 4); idx += 256) {  // 448 float4
        int row = idx / (DIN / 4), c4 = idx % (DIN / 4);
        int n = n0 + row;
        float4 v = make_float4(0.f, 0.f, 0.f, 0.f);
        if (n < N) v = *(const float4*)&x[(size_t)n * DIN + c4 * 4];
        *(float4*)&Asm[row * DIN + c4 * 4] = v;
    }
    __syncthreads();
    float acc[8];
#pragma unroll
    for (int r = 0; r < 8; r++) acc[r] = pb[l];
    const float* Aw = &Asm[(w * 8) * DIN];
#pragma unroll
    for (int kq = 0; kq < DIN / 4; kq++) {  // 14 quads
        float w0 = Wsm[(kq * 4 + 0) * 64 + l];
        float w1 = Wsm[(kq * 4 + 1) * 64 + l];
        float w2 = Wsm[(kq * 4 + 2) * 64 + l];
        float w3 = Wsm[(kq * 4 + 3) * 64 + l];
#pragma unroll
        for (int r = 0; r < 8; r++) {
            float4 av = *(const float4*)&Aw[r * DIN + kq * 4];
            acc[r] = fmaf(av.x, w0, acc[r]);
            acc[r] = fmaf(av.y, w1, acc[r]);
            acc[r] = fmaf(av.z, w2, acc[r]);
            acc[r] = fmaf(av.w, w3, acc[r]);
        }
    }
#pragma unroll
    for (int r = 0; r < 8; r++) {
        int n = n0 + w * 8 + r;
        if (n < N) h[(size_t)n * LD + l] = acc[r];  // pad cols get 0 (W/b pad = 0)
    }
}

// One wave per node; lane = padded column; register accumulate; no LDS.
// BN+ReLU of the previous layer folded into the gather (and the self term).
template <bool BN_IN>
__global__ void k_agg(const float* __restrict__ hin, float* __restrict__ zout,
                      const int* __restrict__ rowptr, const int* __restrict__ csr,
                      const float* __restrict__ gam, const float* __restrict__ bet,
                      const float* __restrict__ stats, float invN,
                      const float* __restrict__ eps_gin, int l, int N) {
    int wave = threadIdx.x >> 6;
    int lane = threadIdx.x & 63;
    int n = blockIdx.x * 4 + wave;
    if (n >= N) return;
    float scr = 1.f, shr = 0.f;
    if (BN_IN) {
        if (lane < DV) {
            float mu = stats[lane] * invN;
            float var = stats[64 + lane] * invN - mu * mu;
            float s = gam[lane] * rsqrtf(var + 1e-5f);
            scr = s;
            shr = bet[lane] - mu * s;
        } else {
            scr = 0.f;
            shr = 0.f;
        }
    }
    int s = rowptr[n], e = rowptr[n + 1];
    float acc = 0.f;
    int deg = e - s;
    for (int base = 0; base < deg; base += 64) {
        int m = min(64, deg - base);
        int sv = (lane < m) ? csr[s + base + lane] : 0;
        int i = 0;
        for (; i + 8 <= m; i += 8) {
            int s0 = __shfl(sv, i), s1 = __shfl(sv, i + 1);
            int s2 = __shfl(sv, i + 2), s3 = __shfl(sv, i + 3);
            int s4 = __shfl(sv, i + 4), s5 = __shfl(sv, i + 5);
            int s6 = __shfl(sv, i + 6), s7 = __shfl(sv, i + 7);
            float v0 = hin[(size_t)s0 * LD + lane];
            float v1 = hin[(size_t)s1 * LD + lane];
            float v2 = hin[(size_t)s2 * LD + lane];
            float v3 = hin[(size_t)s3 * LD + lane];
            float v4 = hin[(size_t)s4 * LD + lane];
            float v5 = hin[(size_t)s5 * LD + lane];
            float v6 = hin[(size_t)s6 * LD + lane];
            float v7 = hin[(size_t)s7 * LD + lane];
            if (BN_IN) {
                v0 = fmaxf(0.f, fmaf(v0, scr, shr));
                v1 = fmaxf(0.f, fmaf(v1, scr, shr));
                v2 = fmaxf(0.f, fmaf(v2, scr, shr));
                v3 = fmaxf(0.f, fmaf(v3, scr, shr));
                v4 = fmaxf(0.f, fmaf(v4, scr, shr));
                v5 = fmaxf(0.f, fmaf(v5, scr, shr));
                v6 = fmaxf(0.f, fmaf(v6, scr, shr));
                v7 = fmaxf(0.f, fmaf(v7, scr, shr));
            }
            acc += v0 + v1 + v2 + v3 + v4 + v5 + v6 + v7;
        }
        for (; i < m; i++) {
            int sidx = __shfl(sv, i);
            float v = hin[(size_t)sidx * LD + lane];
            if (BN_IN) v = fmaxf(0.f, fmaf(v, scr, shr));
            acc += v;
        }
    }
    float eps1 = 1.f + eps_gin[l];
    float self = hin[(size_t)n * LD + lane];
    if (BN_IN) self = fmaxf(0.f, fmaf(self, scr, shr));
    zout[(size_t)n * LD + lane] = acc + eps1 * self;
}

// Tiled GEMM: block = 32 rows, wave = 8 rows, lane = output col. in:[N][64] (cols<49
// valid) @ W:[49][49]. Optional BN+ReLU on input (folded into A staging); column
// sum/sumsq of output accumulated via LDS then one atomic pass per block.
// In-place safe (tile staged before written; tiles disjoint across blocks).
template <bool BN_IN>
__global__ __launch_bounds__(256, 4)
void k_gemm(const float* in, float* out,
            const float* __restrict__ W, const float* __restrict__ bias,
            const float* __restrict__ gam, const float* __restrict__ bet,
            const float* __restrict__ statsIn, float* __restrict__ statsOut,
            float invN, int N) {
    __shared__ __align__(16) float Asm[32 * 64];
    __shared__ __align__(16) float Wsm[52 * 64];
    __shared__ float pb[64];
    __shared__ float scs[64], shs[64];
    __shared__ float st0[64], st1[64];
    int t = threadIdx.x;
    int w = t >> 6, l = t & 63;
    int n0 = blockIdx.x << 5;
    if (t < 64) {
        st0[t] = 0.f;
        st1[t] = 0.f;
        pb[t] = (t < DV) ? bias[t] : 0.f;
        if (BN_IN) {
            float scv = 0.f, shv = 0.f;
            if (t < DV) {
                float mu = statsIn[t] * invN;
                float var = statsIn[64 + t] * invN - mu * mu;
                float s = gam[t] * rsqrtf(var + 1e-5f);
                scv = s;
                shv = bet[t] - mu * s;
            }
            scs[t] = scv;
            shs[t] = shv;
        }
    }
    for (int idx = t; idx < 52 * 64; idx += 256) {
        int k = idx >> 6, c = idx & 63;
        Wsm[idx] = (k < DV && c < DV) ? W[k * DV + c] : 0.f;
    }
    __syncthreads();
    for (int idx = t; idx < 512; idx += 256) {
        int row = idx >> 4, c4 = idx & 15;
        int n = n0 + row;
        float4 v = make_float4(0.f, 0.f, 0.f, 0.f);
        if (n < N) {
            v = *(const float4*)&in[(size_t)n * LD + c4 * 4];
            if (BN_IN) {
                int c = c4 * 4;
                v.x = fmaxf(0.f, fmaf(v.x, scs[c + 0], shs[c + 0]));
                v.y = fmaxf(0.f, fmaf(v.y, scs[c + 1], shs[c + 1]));
                v.z = fmaxf(0.f, fmaf(v.z, scs[c + 2], shs[c + 2]));
                v.w = fmaxf(0.f, fmaf(v.w, scs[c + 3], shs[c + 3]));
            }
        }
        *(float4*)&Asm[row * 64 + c4 * 4] = v;
    }
    __syncthreads();
    float acc[8];
#pragma unroll
    for (int r = 0; r < 8; r++) acc[r] = pb[l];
    const float* Aw = &Asm[(w * 8) * 64];
#pragma unroll
    for (int kq = 0; kq < 13; kq++) {
        float w0 = Wsm[(kq * 4 + 0) * 64 + l];
        float w1 = Wsm[(kq * 4 + 1) * 64 + l];
        float w2 = Wsm[(kq * 4 + 2) * 64 + l];
        float w3 = Wsm[(kq * 4 + 3) * 64 + l];
#pragma unroll
        for (int r = 0; r < 8; r++) {
            float4 av = *(const float4*)&Aw[r * 64 + kq * 4];
            acc[r] = fmaf(av.x, w0, acc[r]);
            acc[r] = fmaf(av.y, w1, acc[r]);
            acc[r] = fmaf(av.z, w2, acc[r]);
            acc[r] = fmaf(av.w, w3, acc[r]);
        }
    }
    float s = 0.f, q = 0.f;
#pragma unroll
    for (int r = 0; r < 8; r++) {
        int n = n0 + w * 8 + r;
        if (n < N) {
            out[(size_t)n * LD + l] = acc[r];  // pad cols get 0 (W/b pad = 0)
            s += acc[r];
            q += acc[r] * acc[r];
        }
    }
    atomicAdd(&st0[l], s);
    atomicAdd(&st1[l], q);
    __syncthreads();
    if (t < DV) {
        atomicAdd(&statsOut[t], st0[t]);
        atomicAdd(&statsOut[64 + t], st1[t]);
    }
}

// batch sorted: one wave per graph, binary search range, fold final BN+ReLU.
__global__ void k_pool(const float* __restrict__ h, const int* __restrict__ batch,
                       const float* __restrict__ gam, const float* __restrict__ bet,
                       const float* __restrict__ stats, float invN,
                       float* __restrict__ out, int N) {
    int g = blockIdx.x;
    int lane = threadIdx.x;
    int lo, hi;
    {
        int a = 0, b = N;
        while (a < b) { int mid = (a + b) >> 1; if (batch[mid] < g) a = mid + 1; else b = mid; }
        lo = a;
    }
    {
        int a = lo, b = N;
        while (a < b) { int mid = (a + b) >> 1; if (batch[mid] < g + 1) a = mid + 1; else b = mid; }
        hi = a;
    }
    float scv = 0.f, shv = 0.f;
    if (lane < DV) {
        float mu = stats[lane] * invN;
        float var = stats[64 + lane] * invN - mu * mu;
        float s = gam[lane] * rsqrtf(var + 1e-5f);
        scv = s;
        shv = bet[lane] - mu * s;
    }
    float a0 = 0.f, a1 = 0.f, a2 = 0.f, a3 = 0.f;
    int n2 = lo;
    for (; n2 + 4 <= hi; n2 += 4) {
        a0 += fmaxf(0.f, fmaf(h[(size_t)(n2 + 0) * LD + lane], scv, shv));
        a1 += fmaxf(0.f, fmaf(h[(size_t)(n2 + 1) * LD + lane], scv, shv));
        a2 += fmaxf(0.f, fmaf(h[(size_t)(n2 + 2) * LD + lane], scv, shv));
        a3 += fmaxf(0.f, fmaf(h[(size_t)(n2 + 3) * LD + lane], scv, shv));
    }
    for (; n2 < hi; n2++)
        a0 += fmaxf(0.f, fmaf(h[(size_t)n2 * LD + lane], scv, shv));
    float acc = (a0 + a1) + (a2 + a3);
    float cnt = (float)max(hi - lo, 1);
    if (lane < DV) out[g * DV + lane] = acc / cnt;
}

extern "C" void kernel_launch(void* const* d_in, const int* in_sizes, int n_in,
                              void* d_out, int out_size, void* d_ws, size_t ws_size,
                              hipStream_t stream) {
    const float* x = (const float*)d_in[0];
    const float* W0 = (const float*)d_in[1];
    const float* b0 = (const float*)d_in[2];
    const float* W1 = (const float*)d_in[3];
    const float* b1 = (const float*)d_in[4];
    const float* g1 = (const float*)d_in[5];
    const float* be1 = (const float*)d_in[6];
    const float* W2 = (const float*)d_in[7];
    const float* b2 = (const float*)d_in[8];
    const float* g2 = (const float*)d_in[9];
    const float* be2 = (const float*)d_in[10];
    const float* eps_gin = (const float*)d_in[11];
    const int* edge_index = (const int*)d_in[12];
    const int* batch = (const int*)d_in[13];
    float* out = (float*)d_out;

    int N = in_sizes[0] / DIN;
    int E = in_sizes[12] / 2;
    const int* esrc = edge_index;
    const int* edst = edge_index + E;
    int NB = (N + BSZ - 1) >> BSH;

    char* ws = (char*)d_ws;
    size_t off = 0;
    auto alloc = [&](size_t bytes) -> void* {
        void* p = ws + off;
        off = (off + bytes + 255) & ~(size_t)255;
        return p;
    };
    float* P = (float*)alloc((size_t)N * LD * 4);   // activations (ping)
    float* A = (float*)alloc((size_t)N * LD * 4);   // activations (pong)
    unsigned int* ep = (unsigned int*)alloc((size_t)E * 4);
    int* csr = (int*)alloc((size_t)E * 4);
    int* rowptr = (int*)alloc((size_t)(N + 1) * 4);
    int* ghist = (int*)alloc((size_t)NB * 4);
    int* bstart = (int*)alloc((size_t)(NB + 1) * 4);
    int* cursor = (int*)alloc((size_t)NB * 4);
    float* stats = (float*)alloc(NLAY * 2 * 128 * 4);
    (void)ws_size;  // needs ~65 MB

    float invN = 1.f / (float)N;
    int gT = (N + 31) / 32;  // 32-row tiles for lin0/gemm

    k_zero<<<8, 256, 0, stream>>>(ghist, NB, stats);
    k_hist_b<<<1024, 256, 0, stream>>>(edst, E, ghist, NB);
    k_scanb<<<1, 256, 0, stream>>>(ghist, NB, bstart, cursor);
    k_scatter_b<<<256, 256, 0, stream>>>(esrc, edst, E, cursor, ep, NB);
    k_sortb<<<NB, 256, 0, stream>>>(ep, bstart, csr, rowptr, N, NB);
    k_lin0<<<gT, 256, 0, stream>>>(x, W0, b0, P, N);

    for (int l = 0; l < NLAY; l++) {
        float* S1 = stats + (l * 2 + 0) * 128;
        float* S2 = stats + (l * 2 + 1) * 128;
        if (l == 0) {
            k_agg<false><<<(N + 3) / 4, 256, 0, stream>>>(P, A, rowptr, csr, nullptr,
                                                          nullptr, nullptr, invN,
                                                          eps_gin, l, N);
        } else {
            float* S2p = stats + ((l - 1) * 2 + 1) * 128;
            k_agg<true><<<(N + 3) / 4, 256, 0, stream>>>(P, A, rowptr, csr,
                                                         g2 + (l - 1) * DV,
                                                         be2 + (l - 1) * DV, S2p, invN,
                                                         eps_gin, l, N);
        }
        k_gemm<false><<<gT, 256, 0, stream>>>(A, A, W1 + (size_t)l * DV * DV, b1 + l * DV,
                                              nullptr, nullptr, nullptr, S1, invN, N);
        k_gemm<true><<<gT, 256, 0, stream>>>(A, P, W2 + (size_t)l * DV * DV, b2 + l * DV,
                                             g1 + l * DV, be1 + l * DV, S1, S2, invN, N);
    }
    float* S2last = stats + ((NLAY - 1) * 2 + 1) * 128;
    k_pool<<<NGR, 64, 0, stream>>>(P, batch, g2 + (NLAY - 1) * DV, be2 + (NLAY - 1) * DV,
                                   S2last, invN, out, N);
}